// Round 5
// baseline (308.102 us; speedup 1.0000x reference)
//
#include <hip/hip_runtime.h>

// LightLIF fused step on MI355X (gfx950) — round 9.
//
//   A = [inputs | z]            : [4096, 3072] fp32   (M x K)
//   Bm = [w_in ; w_rec*(1-eye)] : [3072, 2048] fp32   (K x N), B pre-scaled by 256
//   i_t = A @ Bm    (fp32-accurate via f16 Markidis split, 3 MFMA passes)
//   new_v = DECAY*v + (1-DECAY)*i_t - 0.615*z ; spike vs THR
//   d_out = [new_z (M*N) | new_v (M*N)]
//
// Round-9: four GEMM schedule variants (r5-r8) all landed 160-171 us at
// 38-45% MfmaUtil -> schedule is not the lever. lif_gemm reverts to the
// round-7 measured best (128x128 tile, 4 waves, 64 KB LDS dbuf, 2 blocks/CU,
// 160.5 us). The unexamined cost is the OTHER ~130 us: prep_ab (roofline
// ~23 us). Rebuilt prep: B-split gets its own blocks (grid y 32..47) with
// all 256 threads active (2 threads/column, 16 k each) instead of
// half-idle piggybacking; A-split unchanged. Outputs bit-identical.

#define M_DIM 4096
#define N_DIM 2048
#define K_DIM 3072
#define KA    1024
#define BK    32
#define NSTEP (K_DIM / BK)          // 96
#define AIMG  4096                  // halves: 4 k-octets x 128 rows x 8
#define BIMG  4096                  // halves: 4 k-octets x 128 cols x 8
#define BUF_HALVES (AIMG + AIMG + BIMG + BIMG)  // 16384 halves = 32 KB
#define NBUF 2
#define LDS_BYTES (NBUF * BUF_HALVES * 2)       // 65536 B = 64 KB

#define SZ_AH ((size_t)32 * 96 * AIMG * 2)  // 25,165,824 B (one of hi/lo)
#define SZ_BH ((size_t)16 * 96 * BIMG * 2)  // 12,582,912 B
#define WS_NEEDED (2 * SZ_AH + 2 * SZ_BH)   // 75,497,472 B

typedef _Float16 f16x8 __attribute__((ext_vector_type(8)));
typedef float    f32x4 __attribute__((ext_vector_type(4)));

#define GLOBAL_AS(p) ((const __attribute__((address_space(1))) void*)(p))
#define LDS_AS(p)    ((__attribute__((address_space(3))) void*)(p))

// hi/lo split with lo pre-scaled by 2048 (RNE conversions)
#define SPLIT(x, dsthi, dstlo, idx)                                  \
  {                                                                  \
    _Float16 _h = (_Float16)(x);                                     \
    float    _r = ((x) - (float)_h) * 2048.0f;                       \
    dsthi[idx] = _h;                                                 \
    dstlo[idx] = (_Float16)_r;                                       \
  }

// ---------------------------------------------------------------------------
// prep_ab: grid (96 kt, 48), block 256.
//   blockIdx.y < 32  : A-split for bm panel bg (128 rows x 32 k),
//                      layout [kg 4][row 128][8].
//   blockIdx.y >= 32 : B-split for bn panel bg-32 (32 k x 128 cols),
//                      layout [kg 4][col 128][8]; 2 threads per column
//                      (k-halves), all 256 threads active.
// ---------------------------------------------------------------------------
__global__ __launch_bounds__(256) void prep_ab(
    const float* __restrict__ inputs, const float* __restrict__ z,
    const float* __restrict__ w_in, const float* __restrict__ w_rec,
    _Float16* __restrict__ ahi, _Float16* __restrict__ alo,
    _Float16* __restrict__ bhi, _Float16* __restrict__ blo) {
  const int kt = blockIdx.x;
  const int bg = blockIdx.y;
  const int t = threadIdx.x;

  if (bg < 32) {
    // ---- A-split (identical math/layout to round 7)
    const int s = t & 3;       // k-octet 0..3
    const int rr = t >> 2;     // 0..63
    const int k0 = kt * BK + s * 8;
    const size_t img = ((size_t)bg * 96 + kt) * AIMG;
#pragma unroll
    for (int p = 0; p < 2; ++p) {
      const int row = p * 64 + rr;
      const int rg = bg * 128 + row;
      const float* src = (kt < 32) ? inputs + (size_t)rg * KA + k0
                                   : z + (size_t)rg * N_DIM + (k0 - KA);
      const float4 f0 = *(const float4*)(src);
      const float4 f1 = *(const float4*)(src + 4);
      f16x8 hi, lo;
      SPLIT(f0.x, hi, lo, 0);
      SPLIT(f0.y, hi, lo, 1);
      SPLIT(f0.z, hi, lo, 2);
      SPLIT(f0.w, hi, lo, 3);
      SPLIT(f1.x, hi, lo, 4);
      SPLIT(f1.y, hi, lo, 5);
      SPLIT(f1.z, hi, lo, 6);
      SPLIT(f1.w, hi, lo, 7);
      const size_t o = img + (size_t)s * 1024 + (size_t)row * 8;
      *(f16x8*)&ahi[o] = hi;
      *(f16x8*)&alo[o] = lo;
    }
  } else {
    // ---- B-split: full block active; thread = (col, k-half)
    const int bn = bg - 32;         // 0..15
    const int c = t & 127;          // column 0..127
    const int kh = t >> 7;          // 0..1 (k 0-15 / 16-31 of this tile)
    const int ng = bn * 128 + c;
    const int k0 = kt * BK + kh * 16;
    f16x8 hi[2], lo[2];
#pragma unroll
    for (int kk = 0; kk < 16; ++kk) {
      const int k = k0 + kk;
      float x = (k < KA) ? w_in[(size_t)k * N_DIM + ng]
                         : w_rec[(size_t)(k - KA) * N_DIM + ng];
      if (k >= KA && (k - KA) == ng) x = 0.0f;   // zero diagonal of w_rec
      x *= 256.0f;                               // keep hi-parts normal in f16
      SPLIT(x, hi[kk >> 3], lo[kk >> 3], kk & 7);
    }
    const size_t img = ((size_t)bn * 96 + kt) * BIMG + (size_t)c * 8;
#pragma unroll
    for (int q = 0; q < 2; ++q) {
      *(f16x8*)&bhi[img + (size_t)(kh * 2 + q) * 1024] = hi[q];
      *(f16x8*)&blo[img + (size_t)(kh * 2 + q) * 1024] = lo[q];
    }
  }
}

// ---------------------------------------------------------------------------
// GEMM + fused LIF epilogue — round-7 measured best (160.5 us), verbatim.
// grid (16 bn, 32 bm) [bn on x -> each XCD owns 2 bn panels, B L2-resident].
// Block 256 = 4 waves (2m x 2n of 64x64). 64 KB LDS double-buffer ->
// 2 blocks/CU; independent block barriers give inter-block phase overlap.
// Each wave stages exactly one 8 KB image (8 x 16B global_load_lds).
// ---------------------------------------------------------------------------
__global__ __launch_bounds__(256, 2) void lif_gemm(
    const _Float16* __restrict__ ahi, const _Float16* __restrict__ alo,
    const _Float16* __restrict__ bhi, const _Float16* __restrict__ blo,
    const float* __restrict__ vin, const float* __restrict__ zin,
    float* __restrict__ out) {
  extern __shared__ __align__(16) _Float16 sbuf[];  // NBUF * BUF_HALVES = 64 KB

  const int tid = threadIdx.x;
  const int bn = blockIdx.x;   // 16; consecutive ids vary bn -> B XCD-local
  const int bm = blockIdx.y;   // 32
  const int lane = tid & 63;
  const int wid = tid >> 6;       // 0..3
  const int wm = wid & 1;         // m-half (2 x 64)
  const int wn = wid >> 1;        // n-half (2 x 64)
  const int lr = lane & 15;
  const int kg = lane >> 4;

  // staging role: wave 0 -> Ahi, 1 -> Alo, 2 -> Bhi, 3 -> Blo (8 KB each)
  const _Float16* gsrc;
  int lofs;        // wave's image offset within a buffer (halves)
  if (wid == 0)      { gsrc = ahi + (size_t)bm * 96 * AIMG; lofs = 0; }
  else if (wid == 1) { gsrc = alo + (size_t)bm * 96 * AIMG; lofs = AIMG; }
  else if (wid == 2) { gsrc = bhi + (size_t)bn * 96 * BIMG; lofs = 2 * AIMG; }
  else               { gsrc = blo + (size_t)bn * 96 * BIMG; lofs = 2 * AIMG + BIMG; }
  gsrc += (size_t)lane * 8;  // per-lane 16 B (matches HW dest lane*16)

// every wave: 8 x 16B global_load_lds per tile (one 4096-half image)
#define STAGE(tile)                                                          \
  do {                                                                       \
    const _Float16* g_ = gsrc + (size_t)(tile) * 4096;                       \
    _Float16* l_ = sbuf + ((tile) & 1) * BUF_HALVES + lofs;                  \
    _Pragma("unroll")                                                        \
    for (int q_ = 0; q_ < 8; ++q_)                                           \
      __builtin_amdgcn_global_load_lds(GLOBAL_AS(g_ + q_ * 512),             \
                                       LDS_AS(l_ + q_ * 512), 16, 0, 0);     \
  } while (0)

  // frag offsets (halves): A image [kg][row][8], B image [kg][col][8]
  const int abase = kg * 1024 + (wm * 64 + lr) * 8;
  const int bbase = kg * 1024 + (wn * 64 + lr) * 8;

  f32x4 acc0[4][4];  // hi*hi (scale 256)
  f32x4 acc1[4][4];  // hi*lo + lo*hi (scale 256*2048)
#pragma unroll
  for (int i = 0; i < 4; ++i)
#pragma unroll
    for (int j = 0; j < 4; ++j) {
      acc0[i][j] = (f32x4)0.0f;
      acc1[i][j] = (f32x4)0.0f;
    }

  // 12-MFMA cluster, same accumulation order as rounds 4-8 (bit-identical)
#define CLUSTER(J)                                                            \
    __builtin_amdgcn_s_setprio(1);                                            \
    _Pragma("unroll")                                                         \
    for (int i_ = 0; i_ < 4; ++i_)                                            \
      acc0[i_][J] = __builtin_amdgcn_mfma_f32_16x16x32_f16(ah[i_], bh, acc0[i_][J], 0, 0, 0); \
    _Pragma("unroll")                                                         \
    for (int i_ = 0; i_ < 4; ++i_)                                            \
      acc1[i_][J] = __builtin_amdgcn_mfma_f32_16x16x32_f16(ah[i_], bl, acc1[i_][J], 0, 0, 0); \
    _Pragma("unroll")                                                         \
    for (int i_ = 0; i_ < 4; ++i_)                                            \
      acc1[i_][J] = __builtin_amdgcn_mfma_f32_16x16x32_f16(al[i_], bh, acc1[i_][J], 0, 0, 0); \
    __builtin_amdgcn_s_setprio(0);

  // prologue: stage tile 0
  STAGE(0);

  for (int kt = 0; kt < NSTEP; ++kt) {
    // distance-1: STAGE(kt) was issued one full compute phase ago; nothing
    // newer is in flight for this wave -> vmcnt(0) is the exact counted wait.
    asm volatile("s_waitcnt vmcnt(0)" ::: "memory");
    __builtin_amdgcn_s_barrier();
    if (kt + 1 < NSTEP) STAGE(kt + 1);

    const _Float16* base = sbuf + (kt & 1) * BUF_HALVES;
    const _Float16* pBhi = base + 2 * AIMG;
    const _Float16* pBlo = base + 2 * AIMG + BIMG;

    f16x8 ah[4], al[4];
#pragma unroll
    for (int i = 0; i < 4; ++i) {
      ah[i] = *(const f16x8*)&base[abase + i * 128];
      al[i] = *(const f16x8*)&base[AIMG + abase + i * 128];
    }
    f16x8 bh = *(const f16x8*)&pBhi[bbase];
    f16x8 bl = *(const f16x8*)&pBlo[bbase];
#pragma unroll
    for (int j = 0; j < 4; ++j) {
      f16x8 bh_n, bl_n;
      if (j < 3) {  // roll next B-pair under this cluster's MFMAs
        bh_n = *(const f16x8*)&pBhi[bbase + (j + 1) * 128];
        bl_n = *(const f16x8*)&pBlo[bbase + (j + 1) * 128];
      }
      CLUSTER(j)
      if (j < 3) { bh = bh_n; bl = bl_n; }
    }
  }
#undef CLUSTER
#undef STAGE

  // fused LIF epilogue
  const float DECAYF = 0.9512294245007140f;
  const float OMD = 1.0f - DECAYF;
  const float THR = 0.615f;

  float* outZ = out;
  float* outV = out + (size_t)M_DIM * N_DIM;
  const int colbase = bn * 128 + wn * 64;
  const int rowbase = bm * 128 + wm * 64 + kg * 4;

#pragma unroll
  for (int i = 0; i < 4; ++i) {
#pragma unroll
    for (int j = 0; j < 4; ++j) {
      const int col = colbase + j * 16 + lr;
#pragma unroll
      for (int r = 0; r < 4; ++r) {
        const int row = rowbase + i * 16 + r;
        const size_t idx = (size_t)row * N_DIM + col;
        const float it = acc0[i][j][r] * (1.0f / 256.0f) +
                         acc1[i][j][r] * (1.0f / 524288.0f);
        const float vv = vin[idx];
        const float zz = zin[idx];
        const float nv = DECAYF * vv + OMD * it - THR * zz;
        const float vs = (nv - THR) / THR;
        outZ[idx] = (vs > THR) ? 1.0f : 0.0f;
        outV[idx] = nv;
      }
    }
  }
}

// ---------------------------------------------------------------------------
// Fallback (round-1 monolithic kernel) — used only if ws_size < WS_NEEDED.
// ---------------------------------------------------------------------------
#define LDK 40
__global__ __launch_bounds__(256, 2) void lif_kernel(
    const float* __restrict__ inputs, const float* __restrict__ vin,
    const float* __restrict__ zin, const float* __restrict__ w_in,
    const float* __restrict__ w_rec, float* __restrict__ out) {
  __shared__ __align__(16) _Float16 sAhi[128 * LDK];
  __shared__ __align__(16) _Float16 sAlo[128 * LDK];
  __shared__ __align__(16) _Float16 sBhi[128 * LDK];
  __shared__ __align__(16) _Float16 sBlo[128 * LDK];

  const int tid = threadIdx.x;
  const int bn = blockIdx.x;
  const int bm = blockIdx.y;
  const int srow = tid & 127;
  const int skh = tid >> 7;
  const int lane = tid & 63;
  const int wid = tid >> 6;
  const int wm = wid & 1;
  const int wn = wid >> 1;
  const int lr = lane & 15;
  const int kg = lane >> 4;
  const int aoff = (wm * 64 + lr) * LDK + kg * 8;
  const int boff = (wn * 64 + lr) * LDK + kg * 8;

  f32x4 acc0[4][4];
  f32x4 acc1[4][4];
#pragma unroll
  for (int i = 0; i < 4; ++i)
#pragma unroll
    for (int j = 0; j < 4; ++j) {
      acc0[i][j] = (f32x4)0.0f;
      acc1[i][j] = (f32x4)0.0f;
    }

  const int rowg = bm * 128 + srow;
  const int ng = bn * 128 + srow;

  for (int kt = 0; kt < NSTEP; ++kt) {
    const int k0 = kt * BK;
    f16x8 ahi[2], alo[2];
    {
      const float* aptr = (k0 < KA)
          ? inputs + (size_t)rowg * KA + (k0 + skh * 16)
          : zin + (size_t)rowg * N_DIM + (k0 - KA + skh * 16);
#pragma unroll
      for (int q = 0; q < 4; ++q) {
        const float4 f = *(const float4*)(aptr + q * 4);
        const int vi = q >> 1, ei = (q & 1) * 4;
        SPLIT(f.x, ahi[vi], alo[vi], ei + 0);
        SPLIT(f.y, ahi[vi], alo[vi], ei + 1);
        SPLIT(f.z, ahi[vi], alo[vi], ei + 2);
        SPLIT(f.w, ahi[vi], alo[vi], ei + 3);
      }
    }
    f16x8 bhi[2], blo[2];
    {
      const bool isrec = (k0 >= KA);
      const int kbase = k0 - KA + skh * 16;
      const float* bptr = isrec
          ? w_rec + (size_t)kbase * N_DIM + ng
          : w_in + (size_t)(k0 + skh * 16) * N_DIM + ng;
#pragma unroll
      for (int kk = 0; kk < 16; ++kk) {
        float x = bptr[(size_t)kk * N_DIM];
        if (isrec && (kbase + kk == ng)) x = 0.0f;
        x *= 256.0f;
        SPLIT(x, bhi[kk >> 3], blo[kk >> 3], kk & 7);
      }
    }

    __syncthreads();
    {
      _Float16* pA = &sAhi[srow * LDK + skh * 16];
      *(f16x8*)(pA + 0) = ahi[0];
      *(f16x8*)(pA + 8) = ahi[1];
      _Float16* pAl = &sAlo[srow * LDK + skh * 16];
      *(f16x8*)(pAl + 0) = alo[0];
      *(f16x8*)(pAl + 8) = alo[1];
      _Float16* pB = &sBhi[srow * LDK + skh * 16];
      *(f16x8*)(pB + 0) = bhi[0];
      *(f16x8*)(pB + 8) = bhi[1];
      _Float16* pBl = &sBlo[srow * LDK + skh * 16];
      *(f16x8*)(pBl + 0) = blo[0];
      *(f16x8*)(pBl + 8) = blo[1];
    }
    __syncthreads();

    f16x8 ah[4], al[4];
#pragma unroll
    for (int i = 0; i < 4; ++i) {
      ah[i] = *(const f16x8*)&sAhi[aoff + i * 16 * LDK];
      al[i] = *(const f16x8*)&sAlo[aoff + i * 16 * LDK];
    }
#pragma unroll
    for (int j = 0; j < 4; ++j) {
      const f16x8 bh = *(const f16x8*)&sBhi[boff + j * 16 * LDK];
      const f16x8 bl = *(const f16x8*)&sBlo[boff + j * 16 * LDK];
#pragma unroll
      for (int i = 0; i < 4; ++i)
        acc0[i][j] = __builtin_amdgcn_mfma_f32_16x16x32_f16(ah[i], bh, acc0[i][j], 0, 0, 0);
#pragma unroll
      for (int i = 0; i < 4; ++i)
        acc1[i][j] = __builtin_amdgcn_mfma_f32_16x16x32_f16(ah[i], bl, acc1[i][j], 0, 0, 0);
#pragma unroll
      for (int i = 0; i < 4; ++i)
        acc1[i][j] = __builtin_amdgcn_mfma_f32_16x16x32_f16(al[i], bh, acc1[i][j], 0, 0, 0);
    }
  }

  const float DECAYF = 0.9512294245007140f;
  const float OMD = 1.0f - DECAYF;
  const float THR = 0.615f;
  float* outZ = out;
  float* outV = out + (size_t)M_DIM * N_DIM;
  const int colbase = bn * 128 + wn * 64;
  const int rowbase = bm * 128 + wm * 64 + kg * 4;
#pragma unroll
  for (int i = 0; i < 4; ++i) {
#pragma unroll
    for (int j = 0; j < 4; ++j) {
      const int col = colbase + j * 16 + lr;
#pragma unroll
      for (int r = 0; r < 4; ++r) {
        const int row = rowbase + i * 16 + r;
        const size_t idx = (size_t)row * N_DIM + col;
        const float it = acc0[i][j][r] * (1.0f / 256.0f) +
                         acc1[i][j][r] * (1.0f / 524288.0f);
        const float vv = vin[idx];
        const float zz = zin[idx];
        const float nv = DECAYF * vv + OMD * it - THR * zz;
        const float vs = (nv - THR) / THR;
        outZ[idx] = (vs > THR) ? 1.0f : 0.0f;
        outV[idx] = nv;
      }
    }
  }
}

extern "C" void kernel_launch(void* const* d_in, const int* in_sizes, int n_in,
                              void* d_out, int out_size, void* d_ws, size_t ws_size,
                              hipStream_t stream) {
  const float* inputs = (const float*)d_in[0];
  const float* v      = (const float*)d_in[1];
  const float* z      = (const float*)d_in[2];
  const float* w_in   = (const float*)d_in[3];
  const float* w_rec  = (const float*)d_in[4];
  float* out = (float*)d_out;

  if (ws_size >= WS_NEEDED) {
    _Float16* ahi = (_Float16*)d_ws;
    _Float16* alo = (_Float16*)((char*)d_ws + SZ_AH);
    _Float16* bhi = (_Float16*)((char*)d_ws + 2 * SZ_AH);
    _Float16* blo = (_Float16*)((char*)d_ws + 2 * SZ_AH + SZ_BH);

    // allow 64 KB dynamic LDS; idempotent, capture-safe
    static_assert(NBUF * BUF_HALVES * sizeof(_Float16) == 65536, "LDS size");
    (void)hipFuncSetAttribute((const void*)lif_gemm,
                              hipFuncAttributeMaxDynamicSharedMemorySize, LDS_BYTES);

    hipLaunchKernelGGL(prep_ab, dim3(96, 48), dim3(256), 0, stream,
                       inputs, z, w_in, w_rec, ahi, alo, bhi, blo);
    hipLaunchKernelGGL(lif_gemm, dim3(16, 32), dim3(256), LDS_BYTES, stream,
                       ahi, alo, bhi, blo, v, z, out);
  } else {
    hipLaunchKernelGGL(lif_kernel, dim3(16, 32), dim3(256), 0, stream,
                       inputs, v, z, w_in, w_rec, out);
  }
}

// Round 6
// 300.222 us; speedup vs baseline: 1.0262x; 1.0262x over previous
//
#include <hip/hip_runtime.h>

// LightLIF fused step on MI355X (gfx950) — round 10.
//
//   A = [inputs | z]            : [4096, 3072] fp32   (M x K)
//   Bm = [w_in ; w_rec*(1-eye)] : [3072, 2048] fp32   (K x N), B pre-scaled by 256
//   i_t = A @ Bm    (fp32-accurate via f16 Markidis split, 3 MFMA passes)
//   new_v = DECAY*v + (1-DECAY)*i_t - 0.615*z ; spike vs THR
//   d_out = [new_z (M*N) | new_v (M*N)]
//
// Round-10: schedules (r5-r8) never moved the GEMM because the CU-wide LDS
// PORT is ~2050 cy/step of serialized work next to 1862 cy of MFMA. New
// lever: cut LDS traffic in half. A-fragments are wave-private and the image
// layout makes them coalesced 16B/lane loads -> load A-frags DIRECTLY
// global->VGPR (8 dwordx4/wave/step, X/Y one-step-ahead rotation); only B
// goes through LDS (32 KB/block dbuf). LDS/CU/step 2050 -> ~1020 cy.
// Same fragments, same MFMA order -> bit-identical numerics.

#define M_DIM 4096
#define N_DIM 2048
#define K_DIM 3072
#define KA    1024
#define BK    32
#define NSTEP (K_DIM / BK)          // 96
#define AIMG  4096                  // halves: 4 k-octets x 128 rows x 8
#define BIMG  4096                  // halves: 4 k-octets x 128 cols x 8
#define BUF_HALVES (BIMG + BIMG)    // 8192 halves = 16 KB (Bhi|Blo)
#define NBUF 2
#define LDS_BYTES (NBUF * BUF_HALVES * 2)   // 32768 B = 32 KB

#define SZ_AH ((size_t)32 * 96 * AIMG * 2)  // 25,165,824 B (one of hi/lo)
#define SZ_BH ((size_t)16 * 96 * BIMG * 2)  // 12,582,912 B
#define WS_NEEDED (2 * SZ_AH + 2 * SZ_BH)   // 75,497,472 B

typedef _Float16 f16x8 __attribute__((ext_vector_type(8)));
typedef float    f32x4 __attribute__((ext_vector_type(4)));

#define GLOBAL_AS(p) ((const __attribute__((address_space(1))) void*)(p))
#define LDS_AS(p)    ((__attribute__((address_space(3))) void*)(p))

// hi/lo split with lo pre-scaled by 2048 (RNE conversions)
#define SPLIT(x, dsthi, dstlo, idx)                                  \
  {                                                                  \
    _Float16 _h = (_Float16)(x);                                     \
    float    _r = ((x) - (float)_h) * 2048.0f;                       \
    dsthi[idx] = _h;                                                 \
    dstlo[idx] = (_Float16)_r;                                       \
  }

// ---------------------------------------------------------------------------
// prep_ab: grid (96 kt, 48), block 256.  (unchanged from round 9)
//   blockIdx.y < 32  : A-split for bm panel bg, layout [kg 4][row 128][8].
//   blockIdx.y >= 32 : B-split for bn panel bg-32, layout [kg 4][col 128][8];
//                      2 threads per column, all 256 threads active.
// ---------------------------------------------------------------------------
__global__ __launch_bounds__(256) void prep_ab(
    const float* __restrict__ inputs, const float* __restrict__ z,
    const float* __restrict__ w_in, const float* __restrict__ w_rec,
    _Float16* __restrict__ ahi, _Float16* __restrict__ alo,
    _Float16* __restrict__ bhi, _Float16* __restrict__ blo) {
  const int kt = blockIdx.x;
  const int bg = blockIdx.y;
  const int t = threadIdx.x;

  if (bg < 32) {
    // ---- A-split
    const int s = t & 3;       // k-octet 0..3
    const int rr = t >> 2;     // 0..63
    const int k0 = kt * BK + s * 8;
    const size_t img = ((size_t)bg * 96 + kt) * AIMG;
#pragma unroll
    for (int p = 0; p < 2; ++p) {
      const int row = p * 64 + rr;
      const int rg = bg * 128 + row;
      const float* src = (kt < 32) ? inputs + (size_t)rg * KA + k0
                                   : z + (size_t)rg * N_DIM + (k0 - KA);
      const float4 f0 = *(const float4*)(src);
      const float4 f1 = *(const float4*)(src + 4);
      f16x8 hi, lo;
      SPLIT(f0.x, hi, lo, 0);
      SPLIT(f0.y, hi, lo, 1);
      SPLIT(f0.z, hi, lo, 2);
      SPLIT(f0.w, hi, lo, 3);
      SPLIT(f1.x, hi, lo, 4);
      SPLIT(f1.y, hi, lo, 5);
      SPLIT(f1.z, hi, lo, 6);
      SPLIT(f1.w, hi, lo, 7);
      const size_t o = img + (size_t)s * 1024 + (size_t)row * 8;
      *(f16x8*)&ahi[o] = hi;
      *(f16x8*)&alo[o] = lo;
    }
  } else {
    // ---- B-split: full block active; thread = (col, k-half)
    const int bn = bg - 32;         // 0..15
    const int c = t & 127;          // column 0..127
    const int kh = t >> 7;          // 0..1
    const int ng = bn * 128 + c;
    const int k0 = kt * BK + kh * 16;
    f16x8 hi[2], lo[2];
#pragma unroll
    for (int kk = 0; kk < 16; ++kk) {
      const int k = k0 + kk;
      float x = (k < KA) ? w_in[(size_t)k * N_DIM + ng]
                         : w_rec[(size_t)(k - KA) * N_DIM + ng];
      if (k >= KA && (k - KA) == ng) x = 0.0f;   // zero diagonal of w_rec
      x *= 256.0f;                               // keep hi-parts normal in f16
      SPLIT(x, hi[kk >> 3], lo[kk >> 3], kk & 7);
    }
    const size_t img = ((size_t)bn * 96 + kt) * BIMG + (size_t)c * 8;
#pragma unroll
    for (int q = 0; q < 2; ++q) {
      *(f16x8*)&bhi[img + (size_t)(kh * 2 + q) * 1024] = hi[q];
      *(f16x8*)&blo[img + (size_t)(kh * 2 + q) * 1024] = lo[q];
    }
  }
}

// ---------------------------------------------------------------------------
// GEMM + fused LIF epilogue. grid (16 bn, 32 bm), block 256 = 4 waves
// (2m x 2n of 64x64). B via 32 KB LDS dbuf (all 4 waves stage 4 KB each);
// A-frags global->VGPR with one-step-ahead X/Y register rotation.
// vmcnt(0)+barrier per step drains last step's A-reg loads + B staging.
// ---------------------------------------------------------------------------
__global__ __launch_bounds__(256, 2) void lif_gemm(
    const _Float16* __restrict__ ahi, const _Float16* __restrict__ alo,
    const _Float16* __restrict__ bhi, const _Float16* __restrict__ blo,
    const float* __restrict__ vin, const float* __restrict__ zin,
    float* __restrict__ out) {
  extern __shared__ __align__(16) _Float16 sbuf[];  // 2 * 8192 halves = 32 KB

  const int tid = threadIdx.x;
  const int bn = blockIdx.x;   // 16; consecutive ids vary bn -> B XCD-local
  const int bm = blockIdx.y;   // 32
  const int lane = tid & 63;
  const int wid = tid >> 6;       // 0..3
  const int wm = wid & 1;         // m-half (2 x 64)
  const int wn = wid >> 1;        // n-half (2 x 64)
  const int lr = lane & 15;
  const int kg = lane >> 4;

  // frag offsets (halves): A image [kg][row][8], B image [kg][col][8]
  const int abase = kg * 1024 + (wm * 64 + lr) * 8;
  const int bbase = kg * 1024 + (wn * 64 + lr) * 8;

  // A-frag global base pointers (coalesced: rows are 16B-consecutive)
  const _Float16* gAh = ahi + (size_t)bm * 96 * AIMG + abase;
  const _Float16* gAl = alo + (size_t)bm * 96 * AIMG + abase;

  // B staging: each wave stages one 4 KB quarter of [Bhi|Blo]
  const _Float16* gsrcB = ((wid < 2) ? bhi : blo) + (size_t)bn * 96 * BIMG +
                          (size_t)(wid & 1) * 2048 + (size_t)lane * 8;
  const int lofs = wid * 2048;   // buffer layout: [Bhi 0..4095 | Blo 4096..8191]

#define STAGE_B(tile)                                                        \
  do {                                                                       \
    const _Float16* g_ = gsrcB + (size_t)(tile) * BIMG;                      \
    _Float16* l_ = sbuf + ((tile) & 1) * BUF_HALVES + lofs;                  \
    _Pragma("unroll")                                                        \
    for (int q_ = 0; q_ < 4; ++q_)                                           \
      __builtin_amdgcn_global_load_lds(GLOBAL_AS(g_ + q_ * 512),             \
                                       LDS_AS(l_ + q_ * 512), 16, 0, 0);     \
  } while (0)

#define LOAD_A(tile, Ah, Al)                                                 \
  do {                                                                       \
    const size_t o_ = (size_t)(tile) * AIMG;                                 \
    _Pragma("unroll")                                                        \
    for (int i_ = 0; i_ < 4; ++i_) {                                         \
      Ah[i_] = *(const f16x8*)&gAh[o_ + i_ * 128];                           \
      Al[i_] = *(const f16x8*)&gAl[o_ + i_ * 128];                           \
    }                                                                        \
  } while (0)

  f32x4 acc0[4][4];  // hi*hi (scale 256)
  f32x4 acc1[4][4];  // hi*lo + lo*hi (scale 256*2048)
#pragma unroll
  for (int i = 0; i < 4; ++i)
#pragma unroll
    for (int j = 0; j < 4; ++j) {
      acc0[i][j] = (f32x4)0.0f;
      acc1[i][j] = (f32x4)0.0f;
    }

  // 12-MFMA cluster, same accumulation order as rounds 4-9 (bit-identical)
#define CLUSTER(J, Ah, Al)                                                    \
    __builtin_amdgcn_s_setprio(1);                                            \
    _Pragma("unroll")                                                         \
    for (int i_ = 0; i_ < 4; ++i_)                                            \
      acc0[i_][J] = __builtin_amdgcn_mfma_f32_16x16x32_f16(Ah[i_], bh, acc0[i_][J], 0, 0, 0); \
    _Pragma("unroll")                                                         \
    for (int i_ = 0; i_ < 4; ++i_)                                            \
      acc1[i_][J] = __builtin_amdgcn_mfma_f32_16x16x32_f16(Ah[i_], bl, acc1[i_][J], 0, 0, 0); \
    _Pragma("unroll")                                                         \
    for (int i_ = 0; i_ < 4; ++i_)                                            \
      acc1[i_][J] = __builtin_amdgcn_mfma_f32_16x16x32_f16(Al[i_], bh, acc1[i_][J], 0, 0, 0); \
    __builtin_amdgcn_s_setprio(0);

  // One K-step: entry invariant: B(KT) staged (last step), CA holds A(KT)
  // (loaded last step). vmcnt(0) drains those step-old loads; barrier
  // publishes B(KT) and retires B(KT-1)'s readers. Then issue B(KT+1) stage
  // + A(KT+1) reg loads; compute from LDS-B + reg-A.
#define STEP(KT, CAh, CAl, NAh, NAl)                                          \
  {                                                                           \
    asm volatile("s_waitcnt vmcnt(0)" ::: "memory");                          \
    __builtin_amdgcn_s_barrier();                                             \
    if ((KT) + 1 < NSTEP) {                                                   \
      STAGE_B((KT) + 1);                                                      \
      LOAD_A((KT) + 1, NAh, NAl);                                             \
    }                                                                         \
    const _Float16* base_ = sbuf + ((KT) & 1) * BUF_HALVES;                   \
    const _Float16* pBhi_ = base_;                                            \
    const _Float16* pBlo_ = base_ + BIMG;                                     \
    f16x8 bh = *(const f16x8*)&pBhi_[bbase];                                  \
    f16x8 bl = *(const f16x8*)&pBlo_[bbase];                                  \
    _Pragma("unroll")                                                         \
    for (int j = 0; j < 4; ++j) {                                             \
      f16x8 bh_n, bl_n;                                                       \
      if (j < 3) {                                                            \
        bh_n = *(const f16x8*)&pBhi_[bbase + (j + 1) * 128];                  \
        bl_n = *(const f16x8*)&pBlo_[bbase + (j + 1) * 128];                  \
      }                                                                       \
      CLUSTER(j, CAh, CAl)                                                    \
      if (j < 3) { bh = bh_n; bl = bl_n; }                                    \
    }                                                                         \
  }

  // prologue: issue tile-0 staging + A(0) into the X set
  f16x8 aXh[4], aXl[4], aYh[4], aYl[4];
  STAGE_B(0);
  LOAD_A(0, aXh, aXl);

  for (int kt = 0; kt < NSTEP; kt += 2) {
    STEP(kt,     aXh, aXl, aYh, aYl)
    STEP(kt + 1, aYh, aYl, aXh, aXl)
  }
#undef STEP
#undef CLUSTER
#undef LOAD_A
#undef STAGE_B

  // fused LIF epilogue
  const float DECAYF = 0.9512294245007140f;
  const float OMD = 1.0f - DECAYF;
  const float THR = 0.615f;

  float* outZ = out;
  float* outV = out + (size_t)M_DIM * N_DIM;
  const int colbase = bn * 128 + wn * 64;
  const int rowbase = bm * 128 + wm * 64 + kg * 4;

#pragma unroll
  for (int i = 0; i < 4; ++i) {
#pragma unroll
    for (int j = 0; j < 4; ++j) {
      const int col = colbase + j * 16 + lr;
#pragma unroll
      for (int r = 0; r < 4; ++r) {
        const int row = rowbase + i * 16 + r;
        const size_t idx = (size_t)row * N_DIM + col;
        const float it = acc0[i][j][r] * (1.0f / 256.0f) +
                         acc1[i][j][r] * (1.0f / 524288.0f);
        const float vv = vin[idx];
        const float zz = zin[idx];
        const float nv = DECAYF * vv + OMD * it - THR * zz;
        const float vs = (nv - THR) / THR;
        outZ[idx] = (vs > THR) ? 1.0f : 0.0f;
        outV[idx] = nv;
      }
    }
  }
}

// ---------------------------------------------------------------------------
// Fallback (round-1 monolithic kernel) — used only if ws_size < WS_NEEDED.
// ---------------------------------------------------------------------------
#define LDK 40
__global__ __launch_bounds__(256, 2) void lif_kernel(
    const float* __restrict__ inputs, const float* __restrict__ vin,
    const float* __restrict__ zin, const float* __restrict__ w_in,
    const float* __restrict__ w_rec, float* __restrict__ out) {
  __shared__ __align__(16) _Float16 sAhi[128 * LDK];
  __shared__ __align__(16) _Float16 sAlo[128 * LDK];
  __shared__ __align__(16) _Float16 sBhi[128 * LDK];
  __shared__ __align__(16) _Float16 sBlo[128 * LDK];

  const int tid = threadIdx.x;
  const int bn = blockIdx.x;
  const int bm = blockIdx.y;
  const int srow = tid & 127;
  const int skh = tid >> 7;
  const int lane = tid & 63;
  const int wid = tid >> 6;
  const int wm = wid & 1;
  const int wn = wid >> 1;
  const int lr = lane & 15;
  const int kg = lane >> 4;
  const int aoff = (wm * 64 + lr) * LDK + kg * 8;
  const int boff = (wn * 64 + lr) * LDK + kg * 8;

  f32x4 acc0[4][4];
  f32x4 acc1[4][4];
#pragma unroll
  for (int i = 0; i < 4; ++i)
#pragma unroll
    for (int j = 0; j < 4; ++j) {
      acc0[i][j] = (f32x4)0.0f;
      acc1[i][j] = (f32x4)0.0f;
    }

  const int rowg = bm * 128 + srow;
  const int ng = bn * 128 + srow;

  for (int kt = 0; kt < NSTEP; ++kt) {
    const int k0 = kt * BK;
    f16x8 ahi[2], alo[2];
    {
      const float* aptr = (k0 < KA)
          ? inputs + (size_t)rowg * KA + (k0 + skh * 16)
          : zin + (size_t)rowg * N_DIM + (k0 - KA + skh * 16);
#pragma unroll
      for (int q = 0; q < 4; ++q) {
        const float4 f = *(const float4*)(aptr + q * 4);
        const int vi = q >> 1, ei = (q & 1) * 4;
        SPLIT(f.x, ahi[vi], alo[vi], ei + 0);
        SPLIT(f.y, ahi[vi], alo[vi], ei + 1);
        SPLIT(f.z, ahi[vi], alo[vi], ei + 2);
        SPLIT(f.w, ahi[vi], alo[vi], ei + 3);
      }
    }
    f16x8 bhi[2], blo[2];
    {
      const bool isrec = (k0 >= KA);
      const int kbase = k0 - KA + skh * 16;
      const float* bptr = isrec
          ? w_rec + (size_t)kbase * N_DIM + ng
          : w_in + (size_t)(k0 + skh * 16) * N_DIM + ng;
#pragma unroll
      for (int kk = 0; kk < 16; ++kk) {
        float x = bptr[(size_t)kk * N_DIM];
        if (isrec && (kbase + kk == ng)) x = 0.0f;
        x *= 256.0f;
        SPLIT(x, bhi[kk >> 3], blo[kk >> 3], kk & 7);
      }
    }

    __syncthreads();
    {
      _Float16* pA = &sAhi[srow * LDK + skh * 16];
      *(f16x8*)(pA + 0) = ahi[0];
      *(f16x8*)(pA + 8) = ahi[1];
      _Float16* pAl = &sAlo[srow * LDK + skh * 16];
      *(f16x8*)(pAl + 0) = alo[0];
      *(f16x8*)(pAl + 8) = alo[1];
      _Float16* pB = &sBhi[srow * LDK + skh * 16];
      *(f16x8*)(pB + 0) = bhi[0];
      *(f16x8*)(pB + 8) = bhi[1];
      _Float16* pBl = &sBlo[srow * LDK + skh * 16];
      *(f16x8*)(pBl + 0) = blo[0];
      *(f16x8*)(pBl + 8) = blo[1];
    }
    __syncthreads();

    f16x8 ah[4], al[4];
#pragma unroll
    for (int i = 0; i < 4; ++i) {
      ah[i] = *(const f16x8*)&sAhi[aoff + i * 16 * LDK];
      al[i] = *(const f16x8*)&sAlo[aoff + i * 16 * LDK];
    }
#pragma unroll
    for (int j = 0; j < 4; ++j) {
      const f16x8 bh = *(const f16x8*)&sBhi[boff + j * 16 * LDK];
      const f16x8 bl = *(const f16x8*)&sBlo[boff + j * 16 * LDK];
#pragma unroll
      for (int i = 0; i < 4; ++i)
        acc0[i][j] = __builtin_amdgcn_mfma_f32_16x16x32_f16(ah[i], bh, acc0[i][j], 0, 0, 0);
#pragma unroll
      for (int i = 0; i < 4; ++i)
        acc1[i][j] = __builtin_amdgcn_mfma_f32_16x16x32_f16(ah[i], bl, acc1[i][j], 0, 0, 0);
#pragma unroll
      for (int i = 0; i < 4; ++i)
        acc1[i][j] = __builtin_amdgcn_mfma_f32_16x16x32_f16(al[i], bh, acc1[i][j], 0, 0, 0);
    }
  }

  const float DECAYF = 0.9512294245007140f;
  const float OMD = 1.0f - DECAYF;
  const float THR = 0.615f;
  float* outZ = out;
  float* outV = out + (size_t)M_DIM * N_DIM;
  const int colbase = bn * 128 + wn * 64;
  const int rowbase = bm * 128 + wm * 64 + kg * 4;
#pragma unroll
  for (int i = 0; i < 4; ++i) {
#pragma unroll
    for (int j = 0; j < 4; ++j) {
      const int col = colbase + j * 16 + lr;
#pragma unroll
      for (int r = 0; r < 4; ++r) {
        const int row = rowbase + i * 16 + r;
        const size_t idx = (size_t)row * N_DIM + col;
        const float it = acc0[i][j][r] * (1.0f / 256.0f) +
                         acc1[i][j][r] * (1.0f / 524288.0f);
        const float vv = vin[idx];
        const float zz = zin[idx];
        const float nv = DECAYF * vv + OMD * it - THR * zz;
        const float vs = (nv - THR) / THR;
        outZ[idx] = (vs > THR) ? 1.0f : 0.0f;
        outV[idx] = nv;
      }
    }
  }
}

extern "C" void kernel_launch(void* const* d_in, const int* in_sizes, int n_in,
                              void* d_out, int out_size, void* d_ws, size_t ws_size,
                              hipStream_t stream) {
  const float* inputs = (const float*)d_in[0];
  const float* v      = (const float*)d_in[1];
  const float* z      = (const float*)d_in[2];
  const float* w_in   = (const float*)d_in[3];
  const float* w_rec  = (const float*)d_in[4];
  float* out = (float*)d_out;

  if (ws_size >= WS_NEEDED) {
    _Float16* ahi = (_Float16*)d_ws;
    _Float16* alo = (_Float16*)((char*)d_ws + SZ_AH);
    _Float16* bhi = (_Float16*)((char*)d_ws + 2 * SZ_AH);
    _Float16* blo = (_Float16*)((char*)d_ws + 2 * SZ_AH + SZ_BH);

    // allow 32 KB dynamic LDS; idempotent, capture-safe
    static_assert(NBUF * BUF_HALVES * sizeof(_Float16) == 32768, "LDS size");
    (void)hipFuncSetAttribute((const void*)lif_gemm,
                              hipFuncAttributeMaxDynamicSharedMemorySize, LDS_BYTES);

    hipLaunchKernelGGL(prep_ab, dim3(96, 48), dim3(256), 0, stream,
                       inputs, z, w_in, w_rec, ahi, alo, bhi, blo);
    hipLaunchKernelGGL(lif_gemm, dim3(16, 32), dim3(256), LDS_BYTES, stream,
                       ahi, alo, bhi, blo, v, z, out);
  } else {
    hipLaunchKernelGGL(lif_kernel, dim3(16, 32), dim3(256), 0, stream,
                       inputs, v, z, w_in, w_rec, out);
  }
}

// Round 8
// 299.876 us; speedup vs baseline: 1.0274x; 1.0012x over previous
//
#include <hip/hip_runtime.h>

// LightLIF fused step on MI355X (gfx950) — round 12 (= round 11 resubmit,
// hardened: MFMA operands carried as ext_vector_type(8) short bit-patterns,
// the toolchain-verified signature for *_bf16 builtins, instead of __bf16
// vectors; round-11 bench died on container infra, not a kernel verdict).
//
//   A = [inputs | z]            : [4096, 3072] fp32   (M x K)
//   Bm = [w_in ; w_rec*(1-eye)] : [3072, 2048] fp32   (K x N)
//   i_t = A @ Bm    (fp32-accurate via bf16 3-pass split, lo pre-scaled 2^8)
//   new_v = DECAY*v + (1-DECAY)*i_t - 0.615*z ; spike vs THR
//   d_out = [new_z (M*N) | new_v (M*N)]
//
// Rationale (r11): six structural variants (r5-r10) flat at 160-171 us ->
// schedule/LDS-traffic/occupancy are not the levers at this geometry.
// Remaining measured lever: MFMA shape+dtype. 16x16x32_f16 (1955 TF ubench,
// slowest cell) -> 32x32x16_bf16 (2382 TF, +22%): same operand bytes, same
// 16 b128 reads/wave/step, HALF the MFMA instructions (24 vs 48). bf16
// 3-pass split (hi*hi + hi*lo + lo*hi, lo scale 2^8); no B prescale needed.
// No s_setprio (m190: hurts this structure). Loop = r7 measured best.

#define M_DIM 4096
#define N_DIM 2048
#define K_DIM 3072
#define KA    1024
#define BK    32
#define NSTEP (K_DIM / BK)          // 96
#define AIMG  4096                  // ushorts: 4 k-octets x 128 rows x 8
#define BIMG  4096                  // ushorts: 4 k-octets x 128 cols x 8
#define BUF_HALVES (AIMG + AIMG + BIMG + BIMG)  // 16384 ushorts = 32 KB
#define NBUF 2
#define LDS_BYTES (NBUF * BUF_HALVES * 2)       // 65536 B = 64 KB

#define SZ_AH ((size_t)32 * 96 * AIMG * 2)  // 25,165,824 B (one of hi/lo)
#define SZ_BH ((size_t)16 * 96 * BIMG * 2)  // 12,582,912 B
#define WS_NEEDED (2 * SZ_AH + 2 * SZ_BH)   // 75,497,472 B

typedef short    s16x8 __attribute__((ext_vector_type(8)));   // 8 bf16 bits
typedef unsigned short u16x8 __attribute__((ext_vector_type(8)));
typedef float    f32x16 __attribute__((ext_vector_type(16)));
typedef float    f32x4  __attribute__((ext_vector_type(4)));
typedef _Float16 f16x8  __attribute__((ext_vector_type(8)));

#define GLOBAL_AS(p) ((const __attribute__((address_space(1))) void*)(p))
#define LDS_AS(p)    ((__attribute__((address_space(3))) void*)(p))

// ---- bf16 helpers (RNE) --------------------------------------------------
static __device__ __forceinline__ unsigned short f2bf(float x) {
  unsigned u = __float_as_uint(x);
  u += 0x7FFFu + ((u >> 16) & 1u);
  return (unsigned short)(u >> 16);
}
static __device__ __forceinline__ float bf2f(unsigned short h) {
  return __uint_as_float(((unsigned)h) << 16);
}
// hi/lo bf16 split with lo pre-scaled by 256 (2^8)
#define SPLIT_BF(x, dsthi, dstlo, idx)                               \
  {                                                                  \
    unsigned short _h = f2bf(x);                                     \
    float _r = ((x) - bf2f(_h)) * 256.0f;                            \
    dsthi[idx] = _h;                                                 \
    dstlo[idx] = f2bf(_r);                                           \
  }
// f16 split for the fallback kernel
#define SPLIT(x, dsthi, dstlo, idx)                                  \
  {                                                                  \
    _Float16 _h = (_Float16)(x);                                     \
    float    _r = ((x) - (float)_h) * 2048.0f;                       \
    dsthi[idx] = _h;                                                 \
    dstlo[idx] = (_Float16)_r;                                       \
  }

// ---------------------------------------------------------------------------
// prep_ab: grid (96 kt, 48), block 256.
//   blockIdx.y < 32  : A-split for bm panel bg, layout [koct 4][row 128][8].
//   blockIdx.y >= 32 : B-split for bn panel bg-32, layout [koct 4][col 128][8];
//                      2 threads per column, all 256 threads active.
// ---------------------------------------------------------------------------
__global__ __launch_bounds__(256) void prep_ab(
    const float* __restrict__ inputs, const float* __restrict__ z,
    const float* __restrict__ w_in, const float* __restrict__ w_rec,
    unsigned short* __restrict__ ahi, unsigned short* __restrict__ alo,
    unsigned short* __restrict__ bhi, unsigned short* __restrict__ blo) {
  const int kt = blockIdx.x;
  const int bg = blockIdx.y;
  const int t = threadIdx.x;

  if (bg < 32) {
    // ---- A-split
    const int s = t & 3;       // k-octet 0..3
    const int rr = t >> 2;     // 0..63
    const int k0 = kt * BK + s * 8;
    const size_t img = ((size_t)bg * 96 + kt) * AIMG;
#pragma unroll
    for (int p = 0; p < 2; ++p) {
      const int row = p * 64 + rr;
      const int rg = bg * 128 + row;
      const float* src = (kt < 32) ? inputs + (size_t)rg * KA + k0
                                   : z + (size_t)rg * N_DIM + (k0 - KA);
      const float4 f0 = *(const float4*)(src);
      const float4 f1 = *(const float4*)(src + 4);
      u16x8 hi, lo;
      SPLIT_BF(f0.x, hi, lo, 0);
      SPLIT_BF(f0.y, hi, lo, 1);
      SPLIT_BF(f0.z, hi, lo, 2);
      SPLIT_BF(f0.w, hi, lo, 3);
      SPLIT_BF(f1.x, hi, lo, 4);
      SPLIT_BF(f1.y, hi, lo, 5);
      SPLIT_BF(f1.z, hi, lo, 6);
      SPLIT_BF(f1.w, hi, lo, 7);
      const size_t o = img + (size_t)s * 1024 + (size_t)row * 8;
      *(u16x8*)&ahi[o] = hi;
      *(u16x8*)&alo[o] = lo;
    }
  } else {
    // ---- B-split: full block active; thread = (col, k-half)
    const int bn = bg - 32;         // 0..15
    const int c = t & 127;          // column 0..127
    const int kh = t >> 7;          // 0..1
    const int ng = bn * 128 + c;
    const int k0 = kt * BK + kh * 16;
    u16x8 hi[2], lo[2];
#pragma unroll
    for (int kk = 0; kk < 16; ++kk) {
      const int k = k0 + kk;
      float x = (k < KA) ? w_in[(size_t)k * N_DIM + ng]
                         : w_rec[(size_t)(k - KA) * N_DIM + ng];
      if (k >= KA && (k - KA) == ng) x = 0.0f;   // zero diagonal of w_rec
      SPLIT_BF(x, hi[kk >> 3], lo[kk >> 3], kk & 7);
    }
    const size_t img = ((size_t)bn * 96 + kt) * BIMG + (size_t)c * 8;
#pragma unroll
    for (int q = 0; q < 2; ++q) {
      *(u16x8*)&bhi[img + (size_t)(kh * 2 + q) * 1024] = hi[q];
      *(u16x8*)&blo[img + (size_t)(kh * 2 + q) * 1024] = lo[q];
    }
  }
}

// ---------------------------------------------------------------------------
// GEMM + fused LIF epilogue. grid (16 bn, 32 bm), block 256 = 4 waves
// (2m x 2n of 64x64). 64 KB LDS dbuf -> 2 blocks/CU (r7 structure, measured
// best). MFMA = 32x32x16_bf16 (2382 TF ubench): per wave per step 24 MFMA
// (2x2 fragments x 2 k-slices x 3 passes), 16 ds_read_b128. No setprio.
// A operand layout: lane l holds row l&31, k-octet l>>5 of each 16-k slice;
// C/D: col = lane&31, row = (reg&3)+8*(reg>>2)+4*(lane>>5) [m74/m101].
// ---------------------------------------------------------------------------
__global__ __launch_bounds__(256, 2) void lif_gemm(
    const unsigned short* __restrict__ ahi, const unsigned short* __restrict__ alo,
    const unsigned short* __restrict__ bhi, const unsigned short* __restrict__ blo,
    const float* __restrict__ vin, const float* __restrict__ zin,
    float* __restrict__ out) {
  extern __shared__ __align__(16) unsigned short sbuf[];  // 2*16384 u16 = 64 KB

  const int tid = threadIdx.x;
  const int bn = blockIdx.x;   // 16; consecutive ids vary bn -> B XCD-local
  const int bm = blockIdx.y;   // 32
  const int lane = tid & 63;
  const int wid = tid >> 6;       // 0..3
  const int wm = wid & 1;         // m-half (2 x 64)
  const int wn = wid >> 1;        // n-half (2 x 64)
  const int r32 = lane & 31;      // row/col within a 32-block
  const int kh = lane >> 5;       // k-octet within a 16-k slice

  // staging role: wave 0 -> Ahi, 1 -> Alo, 2 -> Bhi, 3 -> Blo (8 KB each)
  const unsigned short* gsrc;
  int lofs;        // wave's image offset within a buffer (ushorts)
  if (wid == 0)      { gsrc = ahi + (size_t)bm * 96 * AIMG; lofs = 0; }
  else if (wid == 1) { gsrc = alo + (size_t)bm * 96 * AIMG; lofs = AIMG; }
  else if (wid == 2) { gsrc = bhi + (size_t)bn * 96 * BIMG; lofs = 2 * AIMG; }
  else               { gsrc = blo + (size_t)bn * 96 * BIMG; lofs = 2 * AIMG + BIMG; }
  gsrc += (size_t)lane * 8;  // per-lane 16 B (matches HW dest lane*16)

// every wave: 8 x 16B global_load_lds per tile (one 4096-ushort image)
#define STAGE(tile)                                                          \
  do {                                                                       \
    const unsigned short* g_ = gsrc + (size_t)(tile) * 4096;                 \
    unsigned short* l_ = sbuf + ((tile) & 1) * BUF_HALVES + lofs;            \
    _Pragma("unroll")                                                        \
    for (int q_ = 0; q_ < 8; ++q_)                                           \
      __builtin_amdgcn_global_load_lds(GLOBAL_AS(g_ + q_ * 512),             \
                                       LDS_AS(l_ + q_ * 512), 16, 0, 0);     \
  } while (0)

  // frag base offsets (ushorts). A image [koct][row][8]: for k-slice s and
  // m-block mb: off = ((s*2 + kh)*128 + wm*64 + mb*32 + r32)*8
  //            = abase + s*2048 + mb*256.  B analogous with wn.
  const int abase = (kh * 128 + wm * 64 + r32) * 8;
  const int bbase = (kh * 128 + wn * 64 + r32) * 8;

  f32x16 acc0[2][2];  // hi*hi (scale 1)
  f32x16 acc1[2][2];  // hi*lo + lo*hi (scale 256)
#pragma unroll
  for (int i = 0; i < 2; ++i)
#pragma unroll
    for (int j = 0; j < 2; ++j) {
      acc0[i][j] = (f32x16)0.0f;
      acc1[i][j] = (f32x16)0.0f;
    }

  // prologue: stage tile 0
  STAGE(0);

  for (int kt = 0; kt < NSTEP; ++kt) {
    // distance-1: STAGE(kt) was issued one full compute phase ago.
    asm volatile("s_waitcnt vmcnt(0)" ::: "memory");
    __builtin_amdgcn_s_barrier();
    if (kt + 1 < NSTEP) STAGE(kt + 1);

    const unsigned short* base = sbuf + (kt & 1) * BUF_HALVES;
    const unsigned short* pAlo = base + AIMG;
    const unsigned short* pBhi = base + 2 * AIMG;
    const unsigned short* pBlo = base + 2 * AIMG + BIMG;

    s16x8 ah[2][2], al[2][2], bh[2][2], bl[2][2];  // [blk][kslice]
#pragma unroll
    for (int s = 0; s < 2; ++s)
#pragma unroll
      for (int mb = 0; mb < 2; ++mb) {
        const int ao = abase + s * 2048 + mb * 256;
        ah[mb][s] = *(const s16x8*)&base[ao];
        al[mb][s] = *(const s16x8*)&pAlo[ao];
      }
#pragma unroll
    for (int s = 0; s < 2; ++s)
#pragma unroll
      for (int nb = 0; nb < 2; ++nb) {
        const int bo = bbase + s * 2048 + nb * 256;
        bh[nb][s] = *(const s16x8*)&pBhi[bo];
        bl[nb][s] = *(const s16x8*)&pBlo[bo];
      }

#pragma unroll
    for (int mb = 0; mb < 2; ++mb)
#pragma unroll
      for (int nb = 0; nb < 2; ++nb) {
        acc0[mb][nb] = __builtin_amdgcn_mfma_f32_32x32x16_bf16(ah[mb][0], bh[nb][0], acc0[mb][nb], 0, 0, 0);
        acc0[mb][nb] = __builtin_amdgcn_mfma_f32_32x32x16_bf16(ah[mb][1], bh[nb][1], acc0[mb][nb], 0, 0, 0);
        acc1[mb][nb] = __builtin_amdgcn_mfma_f32_32x32x16_bf16(ah[mb][0], bl[nb][0], acc1[mb][nb], 0, 0, 0);
        acc1[mb][nb] = __builtin_amdgcn_mfma_f32_32x32x16_bf16(ah[mb][1], bl[nb][1], acc1[mb][nb], 0, 0, 0);
        acc1[mb][nb] = __builtin_amdgcn_mfma_f32_32x32x16_bf16(al[mb][0], bh[nb][0], acc1[mb][nb], 0, 0, 0);
        acc1[mb][nb] = __builtin_amdgcn_mfma_f32_32x32x16_bf16(al[mb][1], bh[nb][1], acc1[mb][nb], 0, 0, 0);
      }
  }
#undef STAGE

  // fused LIF epilogue.  32x32 C layout: col = lane&31,
  // row = (reg&3) + 8*(reg>>2) + 4*(lane>>5)  [m74/m101 verified]
  const float DECAYF = 0.9512294245007140f;
  const float OMD = 1.0f - DECAYF;
  const float THR = 0.615f;

  float* outZ = out;
  float* outV = out + (size_t)M_DIM * N_DIM;
  const int colb = bn * 128 + wn * 64 + r32;
  const int rowb = bm * 128 + wm * 64 + 4 * kh;

#pragma unroll
  for (int mb = 0; mb < 2; ++mb) {
#pragma unroll
    for (int nb = 0; nb < 2; ++nb) {
      const int col = colb + nb * 32;
#pragma unroll
      for (int r = 0; r < 16; ++r) {
        const int row = rowb + mb * 32 + (r & 3) + 8 * (r >> 2);
        const size_t idx = (size_t)row * N_DIM + col;
        const float it = acc0[mb][nb][r] + acc1[mb][nb][r] * (1.0f / 256.0f);
        const float vv = vin[idx];
        const float zz = zin[idx];
        const float nv = DECAYF * vv + OMD * it - THR * zz;
        const float vs = (nv - THR) / THR;
        outZ[idx] = (vs > THR) ? 1.0f : 0.0f;
        outV[idx] = nv;
      }
    }
  }
}

// ---------------------------------------------------------------------------
// Fallback (round-1 monolithic kernel) — used only if ws_size < WS_NEEDED.
// ---------------------------------------------------------------------------
#define LDK 40
__global__ __launch_bounds__(256, 2) void lif_kernel(
    const float* __restrict__ inputs, const float* __restrict__ vin,
    const float* __restrict__ zin, const float* __restrict__ w_in,
    const float* __restrict__ w_rec, float* __restrict__ out) {
  __shared__ __align__(16) _Float16 sAhi[128 * LDK];
  __shared__ __align__(16) _Float16 sAlo[128 * LDK];
  __shared__ __align__(16) _Float16 sBhi[128 * LDK];
  __shared__ __align__(16) _Float16 sBlo[128 * LDK];

  const int tid = threadIdx.x;
  const int bn = blockIdx.x;
  const int bm = blockIdx.y;
  const int srow = tid & 127;
  const int skh = tid >> 7;
  const int lane = tid & 63;
  const int wid = tid >> 6;
  const int wm = wid & 1;
  const int wn = wid >> 1;
  const int lr = lane & 15;
  const int kg = lane >> 4;
  const int aoff = (wm * 64 + lr) * LDK + kg * 8;
  const int boff = (wn * 64 + lr) * LDK + kg * 8;

  f32x4 acc0[4][4];
  f32x4 acc1[4][4];
#pragma unroll
  for (int i = 0; i < 4; ++i)
#pragma unroll
    for (int j = 0; j < 4; ++j) {
      acc0[i][j] = (f32x4)0.0f;
      acc1[i][j] = (f32x4)0.0f;
    }

  const int rowg = bm * 128 + srow;
  const int ng = bn * 128 + srow;

  for (int kt = 0; kt < NSTEP; ++kt) {
    const int k0 = kt * BK;
    f16x8 ahi[2], alo[2];
    {
      const float* aptr = (k0 < KA)
          ? inputs + (size_t)rowg * KA + (k0 + skh * 16)
          : zin + (size_t)rowg * N_DIM + (k0 - KA + skh * 16);
#pragma unroll
      for (int q = 0; q < 4; ++q) {
        const float4 f = *(const float4*)(aptr + q * 4);
        const int vi = q >> 1, ei = (q & 1) * 4;
        SPLIT(f.x, ahi[vi], alo[vi], ei + 0);
        SPLIT(f.y, ahi[vi], alo[vi], ei + 1);
        SPLIT(f.z, ahi[vi], alo[vi], ei + 2);
        SPLIT(f.w, ahi[vi], alo[vi], ei + 3);
      }
    }
    f16x8 bhi[2], blo[2];
    {
      const bool isrec = (k0 >= KA);
      const int kbase = k0 - KA + skh * 16;
      const float* bptr = isrec
          ? w_rec + (size_t)kbase * N_DIM + ng
          : w_in + (size_t)(k0 + skh * 16) * N_DIM + ng;
#pragma unroll
      for (int kk = 0; kk < 16; ++kk) {
        float x = bptr[(size_t)kk * N_DIM];
        if (isrec && (kbase + kk == ng)) x = 0.0f;
        x *= 256.0f;
        SPLIT(x, bhi[kk >> 3], blo[kk >> 3], kk & 7);
      }
    }

    __syncthreads();
    {
      _Float16* pA = &sAhi[srow * LDK + skh * 16];
      *(f16x8*)(pA + 0) = ahi[0];
      *(f16x8*)(pA + 8) = ahi[1];
      _Float16* pAl = &sAlo[srow * LDK + skh * 16];
      *(f16x8*)(pAl + 0) = alo[0];
      *(f16x8*)(pAl + 8) = alo[1];
      _Float16* pB = &sBhi[srow * LDK + skh * 16];
      *(f16x8*)(pB + 0) = bhi[0];
      *(f16x8*)(pB + 8) = bhi[1];
      _Float16* pBl = &sBlo[srow * LDK + skh * 16];
      *(f16x8*)(pBl + 0) = blo[0];
      *(f16x8*)(pBl + 8) = blo[1];
    }
    __syncthreads();

    f16x8 ah[4], al[4];
#pragma unroll
    for (int i = 0; i < 4; ++i) {
      ah[i] = *(const f16x8*)&sAhi[aoff + i * 16 * LDK];
      al[i] = *(const f16x8*)&sAlo[aoff + i * 16 * LDK];
    }
#pragma unroll
    for (int j = 0; j < 4; ++j) {
      const f16x8 bh = *(const f16x8*)&sBhi[boff + j * 16 * LDK];
      const f16x8 bl = *(const f16x8*)&sBlo[boff + j * 16 * LDK];
#pragma unroll
      for (int i = 0; i < 4; ++i)
        acc0[i][j] = __builtin_amdgcn_mfma_f32_16x16x32_f16(ah[i], bh, acc0[i][j], 0, 0, 0);
#pragma unroll
      for (int i = 0; i < 4; ++i)
        acc1[i][j] = __builtin_amdgcn_mfma_f32_16x16x32_f16(ah[i], bl, acc1[i][j], 0, 0, 0);
#pragma unroll
      for (int i = 0; i < 4; ++i)
        acc1[i][j] = __builtin_amdgcn_mfma_f32_16x16x32_f16(al[i], bh, acc1[i][j], 0, 0, 0);
    }
  }

  const float DECAYF = 0.9512294245007140f;
  const float OMD = 1.0f - DECAYF;
  const float THR = 0.615f;
  float* outZ = out;
  float* outV = out + (size_t)M_DIM * N_DIM;
  const int colbase = bn * 128 + wn * 64;
  const int rowbase = bm * 128 + wm * 64 + kg * 4;
#pragma unroll
  for (int i = 0; i < 4; ++i) {
#pragma unroll
    for (int j = 0; j < 4; ++j) {
      const int col = colbase + j * 16 + lr;
#pragma unroll
      for (int r = 0; r < 4; ++r) {
        const int row = rowbase + i * 16 + r;
        const size_t idx = (size_t)row * N_DIM + col;
        const float it = acc0[i][j][r] * (1.0f / 256.0f) +
                         acc1[i][j][r] * (1.0f / 524288.0f);
        const float vv = vin[idx];
        const float zz = zin[idx];
        const float nv = DECAYF * vv + OMD * it - THR * zz;
        const float vs = (nv - THR) / THR;
        outZ[idx] = (vs > THR) ? 1.0f : 0.0f;
        outV[idx] = nv;
      }
    }
  }
}

extern "C" void kernel_launch(void* const* d_in, const int* in_sizes, int n_in,
                              void* d_out, int out_size, void* d_ws, size_t ws_size,
                              hipStream_t stream) {
  const float* inputs = (const float*)d_in[0];
  const float* v      = (const float*)d_in[1];
  const float* z      = (const float*)d_in[2];
  const float* w_in   = (const float*)d_in[3];
  const float* w_rec  = (const float*)d_in[4];
  float* out = (float*)d_out;

  if (ws_size >= WS_NEEDED) {
    unsigned short* ahi = (unsigned short*)d_ws;
    unsigned short* alo = (unsigned short*)((char*)d_ws + SZ_AH);
    unsigned short* bhi = (unsigned short*)((char*)d_ws + 2 * SZ_AH);
    unsigned short* blo = (unsigned short*)((char*)d_ws + 2 * SZ_AH + SZ_BH);

    // allow 64 KB dynamic LDS; idempotent, capture-safe
    static_assert(NBUF * BUF_HALVES * sizeof(unsigned short) == 65536, "LDS size");
    (void)hipFuncSetAttribute((const void*)lif_gemm,
                              hipFuncAttributeMaxDynamicSharedMemorySize, LDS_BYTES);

    hipLaunchKernelGGL(prep_ab, dim3(96, 48), dim3(256), 0, stream,
                       inputs, z, w_in, w_rec, ahi, alo, bhi, blo);
    hipLaunchKernelGGL(lif_gemm, dim3(16, 32), dim3(256), LDS_BYTES, stream,
                       ahi, alo, bhi, blo, v, z, out);
  } else {
    hipLaunchKernelGGL(lif_kernel, dim3(16, 32), dim3(256), 0, stream,
                       inputs, v, z, w_in, w_rec, out);
  }
}